// Round 14
// baseline (200.811 us; speedup 1.0000x reference)
//
#include <hip/hip_runtime.h>

#define NG 16384
#define NT 200

// DPP cross-lane (VALU pipe) — init only
#define DPPF(v, ctrl) __int_as_float(__builtin_amdgcn_update_dpp( \
    0, __float_as_int(v), (ctrl), 0xF, 0xF, true))
#define QP1(v) DPPF(v, 0xB1)   // src lane ^ 1
#define QP2(v) DPPF(v, 0x4E)   // src lane ^ 2
#define RHM(v) DPPF(v, 0x141)  // src lane ^ 7
// LDS-pipe xor-shuffle: lane r reads lane r^e
#define SWZ(v, e) __int_as_float(__builtin_amdgcn_ds_swizzle( \
    __float_as_int(v), ((e) << 10) | 0x1F))

// xor-allgather via DPP (7 ops) — init only
__device__ __forceinline__ void gather8(float v, float* __restrict__ o) {
  o[0] = v;
  o[1] = QP1(v);
  o[2] = QP2(v);
  o[3] = QP2(o[1]);
  o[7] = RHM(v);
  o[6] = RHM(o[1]);
  o[5] = RHM(o[2]);
  o[4] = RHM(o[3]);
}
// xor-allgather via ds_swizzle (LDS pipe, all independent)
__device__ __forceinline__ void gatherS(float v, float* __restrict__ o) {
  o[0] = v;
  o[1] = SWZ(v, 1); o[2] = SWZ(v, 2); o[3] = SWZ(v, 3); o[4] = SWZ(v, 4);
  o[5] = SWZ(v, 5); o[6] = SWZ(v, 6); o[7] = SWZ(v, 7);
}

__global__ __launch_bounds__(256, 2)
void kf_kernel(const float* __restrict__ x,
               const float* __restrict__ m0,
               const float* __restrict__ P0,
               const float* __restrict__ Fm,
               const float* __restrict__ Qm,
               const float* __restrict__ Hm,
               const float* __restrict__ Rm,
               float* __restrict__ out) {
  const int tid = threadIdx.x;
  const int r   = tid & 7;
  const int g   = blockIdx.x * 32 + (tid >> 3);

  // ---- F in LDS, xor layout: Fx[i][d] = F[i][i^d]  (256 B, block-shared) ----
  __shared__ float FxS[64];
  if (tid < 64) {
    const int i = tid >> 3, d = tid & 7;
    FxS[(i << 3) | d] = Fm[(i << 3) | (i ^ d)];
  }

  // ---- small per-lane tables (stay in VGPRs) ----
  float Frt[8], Qt[8], Hd0[8], Hd1[8];
#pragma unroll
  for (int c = 0; c < 8; ++c) {
    Frt[c] = Fm[(r << 3) | (r ^ c)];   // F[r][r^c]
    Qt[c]  = Qm[(r << 3) | (r ^ c)];   // Q[r][r^c]
    Hd0[c] = Hm[r ^ c];                // H[0][r^c]
    Hd1[c] = Hm[8 + (r ^ c)];          // H[1][r^c]
  }
  const float R00 = Rm[0], R01 = Rm[1], R11 = Rm[3];

  // ---- HFd tables: HFd_i[e] = (H F)[i][r^e]  (one-time) ----
  float HFd0[8], HFd1[8];
  {
    float Hs0[8], Hs1[8];
#pragma unroll
    for (int i = 0; i < 8; ++i) { Hs0[i] = Hm[i]; Hs1[i] = Hm[8 + i]; }
    float hfc0 = 0.f, hfc1 = 0.f;   // (H F)[i][r]
#pragma unroll
    for (int jj = 0; jj < 8; ++jj) {
      const float fc = Fm[(jj << 3) | r];   // F[jj][r]
      hfc0 = fmaf(Hs0[jj], fc, hfc0);
      hfc1 = fmaf(Hs1[jj], fc, hfc1);
    }
    gather8(hfc0, HFd0);
    gather8(hfc1, HFd1);
  }

  // ---- per-group state: lane r holds m[r] and P~[d] = P[r][r^d] ----
  float m = m0[(size_t)g * 8 + r];
  float P[8];
#pragma unroll
  for (int d = 0; d < 8; ++d)
    P[d] = P0[(size_t)g * 64 + (r << 3) + (r ^ d)];

  const float* xg = x + (size_t)g * NT * 2;
  float* mo = out + (size_t)g * NT * 2;
  float* co = out + (size_t)NG * NT * 2 + (size_t)g * NT * 4;

  // ---- init measurement mean mm = H m (one-time gather) ----
  float mm0, mm1;
  {
    float MU[8];
    gather8(m, MU);
    float a = Hd0[0] * MU[0], b = Hd1[0] * MU[0];
#pragma unroll
    for (int e = 1; e < 8; ++e) {
      a = fmaf(Hd0[e], MU[e], a);
      b = fmaf(Hd1[e], MU[e], b);
    }
    mm0 = a; mm1 = b;
  }

  // ---- x double-buffer: 4-step batches ----
  float4 xa = *reinterpret_cast<const float4*>(xg);
  float4 xb = *reinterpret_cast<const float4*>(xg + 4);
  float4 na = *reinterpret_cast<const float4*>(xg + 8);
  float4 nb = *reinterpret_cast<const float4*>(xg + 12);

  __syncthreads();   // FxS ready

  // ================= full Riccati, all NT steps ==========================
#pragma unroll 1
  for (int tb = 0; tb < NT; tb += 4) {
#pragma unroll
    for (int j = 0; j < 4; ++j) {
      const int t = tb + j;
      const float x0 = (j == 0) ? xa.x : (j == 1) ? xa.z : (j == 2) ? xb.x : xb.z;
      const float x1 = (j == 0) ? xa.y : (j == 1) ? xa.w : (j == 2) ? xb.y : xb.w;

      // ---- hp_i = (H P)[i][r] via P symmetry (local) ----
      float hp0 = Hd0[0] * P[0];
      float hp1 = Hd1[0] * P[0];
#pragma unroll
      for (int c = 1; c < 8; ++c) {
        hp0 = fmaf(Hd0[c], P[c], hp0);
        hp1 = fmaf(Hd1[c], P[c], hp1);
      }

      // ---- allgather hp on LDS pipe (14 swizzle, independent) ----
      float G0[8], G1[8];
      gatherS(hp0, G0);
      gatherS(hp1, G1);

      // ---- shadow work while swizzles fly ----
      if (r == 0) *reinterpret_cast<float2*>(mo + 2 * t) = make_float2(mm0, mm1);
      const float y0 = x0 - mm0, y1 = x1 - mm1;

      // ---- S = HP H^T + R  (local redundant dots on gathered G) ----
      float sa = G0[0] * Hd0[0], sb = G0[0] * Hd1[0], sc = G1[0] * Hd1[0];
#pragma unroll
      for (int e = 1; e < 8; ++e) {
        sa = fmaf(G0[e], Hd0[e], sa);
        sb = fmaf(G0[e], Hd1[e], sb);
        sc = fmaf(G1[e], Hd1[e], sc);
      }
      const float s00 = R00 + sa, s01 = R01 + sb, s11 = R11 + sc;

      // ---- gain column r: direct 2x2 solve ----
      const float det  = fmaf(s00, s11, -(s01 * s01));
      const float rdet = 1.0f / det;
      const float kt0 = fmaf(s11, hp0, -(s01 * hp1)) * rdet;
      const float kt1 = fmaf(s00, hp1, -(s01 * hp0)) * rdet;

      // ---- mu early; its gather flies under the Ct product ----
      const float mu = fmaf(kt0, y0, fmaf(kt1, y1, m));
      float MU[8];
      gatherS(mu, MU);

      if (r == 1) *reinterpret_cast<float4*>(co + 4 * t) = make_float4(s00, s01, s01, s11);

      // ---- Pu~[d] = P~[d] - kt0*G0[d] - kt1*G1[d] ----
      float Pu[8];
#pragma unroll
      for (int d = 0; d < 8; ++d)
        Pu[d] = fmaf(-kt0, G0[d], fmaf(-kt1, G1[d], P[d]));

      // ---- Ct[e] = C[r^e][r] = sum_d Fx[r^e][e^d] * Pu~[d]  (rows from LDS) ----
      float Ct[8];
#pragma unroll
      for (int e = 0; e < 8; ++e) {
        const float4 fa = *reinterpret_cast<const float4*>(&FxS[((r ^ e) << 3)]);
        const float4 fb = *reinterpret_cast<const float4*>(&FxS[((r ^ e) << 3) | 4]);
        const float f8[8] = {fa.x, fa.y, fa.z, fa.w, fb.x, fb.y, fb.z, fb.w};
        float acc = f8[e ^ 0] * Pu[0];
#pragma unroll
        for (int d = 1; d < 8; ++d) acc = fmaf(f8[e ^ d], Pu[d], acc);
        Ct[e] = acc;
      }

      // ---- transpose on LDS pipe: Crow[e] = C[r][r^e] = SWZ(Ct[e], e) ----
      float Crow[8];
      Crow[0] = Ct[0];
      Crow[1] = SWZ(Ct[1], 1); Crow[2] = SWZ(Ct[2], 2);
      Crow[3] = SWZ(Ct[3], 3); Crow[4] = SWZ(Ct[4], 4);
      Crow[5] = SWZ(Ct[5], 5); Crow[6] = SWZ(Ct[6], 6);
      Crow[7] = SWZ(Ct[7], 7);

      // ---- P~[d] = Qt[d] + sum_e Fx[r^d][d^e] * Crow[e]  (rows from LDS) ----
#pragma unroll
      for (int d = 0; d < 8; ++d) {
        const float4 fa = *reinterpret_cast<const float4*>(&FxS[((r ^ d) << 3)]);
        const float4 fb = *reinterpret_cast<const float4*>(&FxS[((r ^ d) << 3) | 4]);
        const float f8[8] = {fa.x, fa.y, fa.z, fa.w, fb.x, fb.y, fb.z, fb.w};
        float acc = fmaf(f8[d ^ 0], Crow[0], Qt[d]);
#pragma unroll
        for (int e = 1; e < 8; ++e) acc = fmaf(f8[d ^ e], Crow[e], acc);
        P[d] = acc;
      }

      // ---- mean + measurement-mean recursion (MU ready by now) ----
      float ma = Frt[0] * MU[0], h0 = HFd0[0] * MU[0], h1 = HFd1[0] * MU[0];
#pragma unroll
      for (int e = 1; e < 8; ++e) {
        ma = fmaf(Frt[e],  MU[e], ma);
        h0 = fmaf(HFd0[e], MU[e], h0);
        h1 = fmaf(HFd1[e], MU[e], h1);
      }
      m = ma; mm0 = h0; mm1 = h1;
    }
    xa = na; xb = nb;
    int tf = tb + 8; if (tf > NT - 4) tf = NT - 4;
    na = *reinterpret_cast<const float4*>(xg + 2 * tf);
    nb = *reinterpret_cast<const float4*>(xg + 2 * tf + 4);
  }
}

extern "C" void kernel_launch(void* const* d_in, const int* in_sizes, int n_in,
                              void* d_out, int out_size, void* d_ws, size_t ws_size,
                              hipStream_t stream) {
  const float* x  = (const float*)d_in[0];
  const float* m0 = (const float*)d_in[1];
  const float* P0 = (const float*)d_in[2];
  const float* F  = (const float*)d_in[3];
  const float* Q  = (const float*)d_in[4];
  const float* H  = (const float*)d_in[5];
  const float* R  = (const float*)d_in[6];
  float* out = (float*)d_out;

  dim3 grid(NG * 8 / 256), block(256);
  hipLaunchKernelGGL(kf_kernel, grid, block, 0, stream,
                     x, m0, P0, F, Q, H, R, out);
}

// Round 15
// 170.619 us; speedup vs baseline: 1.1770x; 1.1770x over previous
//
#include <hip/hip_runtime.h>

#define NG 16384
#define NT 200

// DPP cross-lane (VALU pipe)
#define DPPF(v, ctrl) __int_as_float(__builtin_amdgcn_update_dpp( \
    0, __float_as_int(v), (ctrl), 0xF, 0xF, true))
#define QP1(v) DPPF(v, 0xB1)   // src lane ^ 1
#define QP2(v) DPPF(v, 0x4E)   // src lane ^ 2
#define RHM(v) DPPF(v, 0x141)  // src lane ^ 7
// LDS-pipe xor-shuffle: lane r reads lane r^e
#define SWZ(v, e) __int_as_float(__builtin_amdgcn_ds_swizzle( \
    __float_as_int(v), ((e) << 10) | 0x1F))

// xor-allgather via DPP (7 ops; chains depth<=2)
__device__ __forceinline__ void gather8(float v, float* __restrict__ o) {
  o[0] = v;
  o[1] = QP1(v);
  o[2] = QP2(v);
  o[3] = QP2(o[1]);
  o[7] = RHM(v);
  o[6] = RHM(o[1]);
  o[5] = RHM(o[2]);
  o[4] = RHM(o[3]);
}
// xor-allgather via ds_swizzle (LDS pipe, all independent)
__device__ __forceinline__ void gatherS(float v, float* __restrict__ o) {
  o[0] = v;
  o[1] = SWZ(v, 1); o[2] = SWZ(v, 2); o[3] = SWZ(v, 3); o[4] = SWZ(v, 4);
  o[5] = SWZ(v, 5); o[6] = SWZ(v, 6); o[7] = SWZ(v, 7);
}

__global__ __launch_bounds__(256, 2)
void kf_kernel(const float* __restrict__ x,
               const float* __restrict__ m0,
               const float* __restrict__ P0,
               const float* __restrict__ Fm,
               const float* __restrict__ Qm,
               const float* __restrict__ Hm,
               const float* __restrict__ Rm,
               float* __restrict__ out) {
  const int tid = threadIdx.x;
  const int r   = tid & 7;
  const int g   = blockIdx.x * 32 + (tid >> 3);

  // ---- per-lane xor-indexed parameter tables ----
  float Frt[8], Qt[8], Hd0[8], Hd1[8];
#pragma unroll
  for (int c = 0; c < 8; ++c) {
    Frt[c] = Fm[(r << 3) | (r ^ c)];   // F[r][r^c]
    Qt[c]  = Qm[(r << 3) | (r ^ c)];   // Q[r][r^c]
    Hd0[c] = Hm[r ^ c];                // H[0][r^c]
    Hd1[c] = Hm[8 + (r ^ c)];          // H[1][r^c]
  }
  const float R00 = Rm[0], R01 = Rm[1], R11 = Rm[3];

  // ---- Fde[dl][c] = F[r^dl][r^c] via DPP chains (one-time) ----
  float Fde[8][8];
  {
    float t1[8], t2[8], t3[8], tt[8];
#pragma unroll
    for (int c = 0; c < 8; ++c) Fde[0][c] = Frt[c];
#pragma unroll
    for (int c = 0; c < 8; ++c) t1[c] = QP1(Frt[c]);
#pragma unroll
    for (int c = 0; c < 8; ++c) Fde[1][c] = t1[1 ^ c];
#pragma unroll
    for (int c = 0; c < 8; ++c) t2[c] = QP2(Frt[c]);
#pragma unroll
    for (int c = 0; c < 8; ++c) Fde[2][c] = t2[2 ^ c];
#pragma unroll
    for (int c = 0; c < 8; ++c) t3[c] = QP2(t1[c]);
#pragma unroll
    for (int c = 0; c < 8; ++c) Fde[3][c] = t3[3 ^ c];
#pragma unroll
    for (int c = 0; c < 8; ++c) tt[c] = RHM(Frt[c]);
#pragma unroll
    for (int c = 0; c < 8; ++c) Fde[7][c] = tt[7 ^ c];
#pragma unroll
    for (int c = 0; c < 8; ++c) tt[c] = RHM(t1[c]);
#pragma unroll
    for (int c = 0; c < 8; ++c) Fde[6][c] = tt[6 ^ c];
#pragma unroll
    for (int c = 0; c < 8; ++c) tt[c] = RHM(t2[c]);
#pragma unroll
    for (int c = 0; c < 8; ++c) Fde[5][c] = tt[5 ^ c];
#pragma unroll
    for (int c = 0; c < 8; ++c) tt[c] = RHM(t3[c]);
#pragma unroll
    for (int c = 0; c < 8; ++c) Fde[4][c] = tt[4 ^ c];
  }

  // ---- HFd tables: HFd_i[e] = (H F)[i][r^e]  (one-time) ----
  float HFd0[8], HFd1[8];
  {
    float Hs0[8], Hs1[8];
#pragma unroll
    for (int i = 0; i < 8; ++i) { Hs0[i] = Hm[i]; Hs1[i] = Hm[8 + i]; }
    float hfc0 = 0.f, hfc1 = 0.f;   // (H F)[i][r]
#pragma unroll
    for (int jj = 0; jj < 8; ++jj) {
      const float fc = Fm[(jj << 3) | r];   // F[jj][r]
      hfc0 = fmaf(Hs0[jj], fc, hfc0);
      hfc1 = fmaf(Hs1[jj], fc, hfc1);
    }
    gather8(hfc0, HFd0);
    gather8(hfc1, HFd1);
  }

  // ---- per-group state: lane r holds m[r] and P~[d] = P[r][r^d] ----
  float m = m0[(size_t)g * 8 + r];
  float P[8];
#pragma unroll
  for (int d = 0; d < 8; ++d)
    P[d] = P0[(size_t)g * 64 + (r << 3) + (r ^ d)];

  const float* xg = x + (size_t)g * NT * 2;
  float* mo = out + (size_t)g * NT * 2;
  float* co = out + (size_t)NG * NT * 2 + (size_t)g * NT * 4;

  // ---- init measurement mean mm = H m (one-time gather) ----
  float mm0, mm1;
  {
    float MU[8];
    gather8(m, MU);
    float a = Hd0[0] * MU[0], b = Hd1[0] * MU[0];
#pragma unroll
    for (int e = 1; e < 8; ++e) {
      a = fmaf(Hd0[e], MU[e], a);
      b = fmaf(Hd1[e], MU[e], b);
    }
    mm0 = a; mm1 = b;
  }

  // ---- x double-buffer: 4-step batches ----
  float4 xa = *reinterpret_cast<const float4*>(xg);
  float4 xb = *reinterpret_cast<const float4*>(xg + 4);
  float4 na = *reinterpret_cast<const float4*>(xg + 8);
  float4 nb = *reinterpret_cast<const float4*>(xg + 12);

  // ================= full Riccati, all NT steps ==========================
#pragma unroll 1
  for (int tb = 0; tb < NT; tb += 4) {
#pragma unroll
    for (int j = 0; j < 4; ++j) {
      const int t = tb + j;
      const float x0 = (j == 0) ? xa.x : (j == 1) ? xa.z : (j == 2) ? xb.x : xb.z;
      const float x1 = (j == 0) ? xa.y : (j == 1) ? xa.w : (j == 2) ? xb.y : xb.w;

      // ---- hp_i = (H P)[i][r] via P symmetry (local) ----
      float hp0 = Hd0[0] * P[0];
      float hp1 = Hd1[0] * P[0];
#pragma unroll
      for (int c = 1; c < 8; ++c) {
        hp0 = fmaf(Hd0[c], P[c], hp0);
        hp1 = fmaf(Hd1[c], P[c], hp1);
      }

      // ---- allgather hp on LDS pipe (14 swizzle, independent) ----
      float G0[8], G1[8];
      gatherS(hp0, G0);
      gatherS(hp1, G1);

      // ---- shadow work while swizzles fly ----
      if (r == 0) *reinterpret_cast<float2*>(mo + 2 * t) = make_float2(mm0, mm1);
      const float y0 = x0 - mm0, y1 = x1 - mm1;

      // ---- S = HP H^T + R  (local redundant dots on gathered G) ----
      float sa = G0[0] * Hd0[0], sb = G0[0] * Hd1[0], sc = G1[0] * Hd1[0];
#pragma unroll
      for (int e = 1; e < 8; ++e) {
        sa = fmaf(G0[e], Hd0[e], sa);
        sb = fmaf(G0[e], Hd1[e], sb);
        sc = fmaf(G1[e], Hd1[e], sc);
      }
      const float s00 = R00 + sa, s01 = R01 + sb, s11 = R11 + sc;

      // ---- gain column r: direct 2x2 solve (fast rcp) ----
      const float det  = fmaf(s00, s11, -(s01 * s01));
      const float rdet = __builtin_amdgcn_rcpf(det);
      const float kt0 = fmaf(s11, hp0, -(s01 * hp1)) * rdet;
      const float kt1 = fmaf(s00, hp1, -(s01 * hp0)) * rdet;

      // ---- mu early; its gather runs on DPP under the Ct product ----
      const float mu = fmaf(kt0, y0, fmaf(kt1, y1, m));
      float MU[8];
      gather8(mu, MU);   // DPP (VALU pipe) — frees the DS pipe

      if (r == 1) *reinterpret_cast<float4*>(co + 4 * t) = make_float4(s00, s01, s01, s11);

      // ---- Pu~[d] = P~[d] - kt0*G0[d] - kt1*G1[d] ----
      float Pu[8];
#pragma unroll
      for (int d = 0; d < 8; ++d)
        Pu[d] = fmaf(-kt0, G0[d], fmaf(-kt1, G1[d], P[d]));

      // ---- C = F Pu (columns, local): Ct[e] = C[r^e][r] ----
      float Ct[8];
#pragma unroll
      for (int e = 0; e < 8; ++e) {
        float acc = Fde[e][0] * Pu[0];
#pragma unroll
        for (int d = 1; d < 8; ++d) acc = fmaf(Fde[e][d], Pu[d], acc);
        Ct[e] = acc;
      }

      // ---- transpose via DPP chains (12 ops, ILP across e) ----
      float Crow[8];
      Crow[0] = Ct[0];
      Crow[1] = QP1(Ct[1]);
      Crow[2] = QP2(Ct[2]);
      {
        const float a3 = QP1(Ct[3]); Crow[3] = QP2(a3);
        const float a4 = QP2(QP1(Ct[4])); Crow[4] = RHM(a4);
        const float a5 = QP2(Ct[5]); Crow[5] = RHM(a5);
        const float a6 = QP1(Ct[6]); Crow[6] = RHM(a6);
        Crow[7] = RHM(Ct[7]);
      }

      // ---- P~[d] = Qt[d] + sum_e Fde[d][e] * Crow[e]  (in place) ----
#pragma unroll
      for (int d = 0; d < 8; ++d) {
        float acc = fmaf(Fde[d][0], Crow[0], Qt[d]);
#pragma unroll
        for (int e = 1; e < 8; ++e) acc = fmaf(Fde[d][e], Crow[e], acc);
        P[d] = acc;
      }

      // ---- mean + measurement-mean recursion (MU ready by now) ----
      float ma = Frt[0] * MU[0], h0 = HFd0[0] * MU[0], h1 = HFd1[0] * MU[0];
#pragma unroll
      for (int e = 1; e < 8; ++e) {
        ma = fmaf(Frt[e],  MU[e], ma);
        h0 = fmaf(HFd0[e], MU[e], h0);
        h1 = fmaf(HFd1[e], MU[e], h1);
      }
      m = ma; mm0 = h0; mm1 = h1;
    }
    xa = na; xb = nb;
    int tf = tb + 8; if (tf > NT - 4) tf = NT - 4;
    na = *reinterpret_cast<const float4*>(xg + 2 * tf);
    nb = *reinterpret_cast<const float4*>(xg + 2 * tf + 4);
  }
}

extern "C" void kernel_launch(void* const* d_in, const int* in_sizes, int n_in,
                              void* d_out, int out_size, void* d_ws, size_t ws_size,
                              hipStream_t stream) {
  const float* x  = (const float*)d_in[0];
  const float* m0 = (const float*)d_in[1];
  const float* P0 = (const float*)d_in[2];
  const float* F  = (const float*)d_in[3];
  const float* Q  = (const float*)d_in[4];
  const float* H  = (const float*)d_in[5];
  const float* R  = (const float*)d_in[6];
  float* out = (float*)d_out;

  dim3 grid(NG * 8 / 256), block(256);
  hipLaunchKernelGGL(kf_kernel, grid, block, 0, stream,
                     x, m0, P0, F, Q, H, R, out);
}

// Round 16
// 163.056 us; speedup vs baseline: 1.2315x; 1.0464x over previous
//
#include <hip/hip_runtime.h>

#define NG 16384
#define NT 200

// DPP cross-lane (VALU pipe) — init only
#define DPPF(v, ctrl) __int_as_float(__builtin_amdgcn_update_dpp( \
    0, __float_as_int(v), (ctrl), 0xF, 0xF, true))
#define QP1(v) DPPF(v, 0xB1)   // src lane ^ 1
#define QP2(v) DPPF(v, 0x4E)   // src lane ^ 2
#define RHM(v) DPPF(v, 0x141)  // src lane ^ 7
// LDS-pipe xor-shuffle: lane r reads lane r^e
#define SWZ(v, e) __int_as_float(__builtin_amdgcn_ds_swizzle( \
    __float_as_int(v), ((e) << 10) | 0x1F))

// xor-allgather via DPP (7 ops) — init only
__device__ __forceinline__ void gather8(float v, float* __restrict__ o) {
  o[0] = v;
  o[1] = QP1(v);
  o[2] = QP2(v);
  o[3] = QP2(o[1]);
  o[7] = RHM(v);
  o[6] = RHM(o[1]);
  o[5] = RHM(o[2]);
  o[4] = RHM(o[3]);
}
// xor-allgather via ds_swizzle (LDS pipe, all independent)
__device__ __forceinline__ void gatherS(float v, float* __restrict__ o) {
  o[0] = v;
  o[1] = SWZ(v, 1); o[2] = SWZ(v, 2); o[3] = SWZ(v, 3); o[4] = SWZ(v, 4);
  o[5] = SWZ(v, 5); o[6] = SWZ(v, 6); o[7] = SWZ(v, 7);
}

__global__ __launch_bounds__(256, 2)
void kf_kernel(const float* __restrict__ x,
               const float* __restrict__ m0,
               const float* __restrict__ P0,
               const float* __restrict__ Fm,
               const float* __restrict__ Qm,
               const float* __restrict__ Hm,
               const float* __restrict__ Rm,
               float* __restrict__ out) {
  const int tid = threadIdx.x;
  const int r   = tid & 7;
  const int g   = blockIdx.x * 32 + (tid >> 3);

  // ---- per-lane xor-indexed parameter tables ----
  float Qt[8], Hd0[8], Hd1[8];
#pragma unroll
  for (int c = 0; c < 8; ++c) {
    Qt[c]  = Qm[(r << 3) | (r ^ c)];   // Q[r][r^c]
    Hd0[c] = Hm[r ^ c];                // H[0][r^c]
    Hd1[c] = Hm[8 + (r ^ c)];          // H[1][r^c]
  }
  const float R00 = Rm[0], R01 = Rm[1], R11 = Rm[3];

  // ---- Fde[dl][c] = F[r^dl][r^c] via DPP chains (one-time) ----
  // Fde[0][c] = F[r][r^c] also serves as the mean-recursion row (old Frt).
  float Fde[8][8];
  {
    float Frt[8], t1[8], t2[8], t3[8], tt[8];
#pragma unroll
    for (int c = 0; c < 8; ++c) Frt[c] = Fm[(r << 3) | (r ^ c)];
#pragma unroll
    for (int c = 0; c < 8; ++c) Fde[0][c] = Frt[c];
#pragma unroll
    for (int c = 0; c < 8; ++c) t1[c] = QP1(Frt[c]);
#pragma unroll
    for (int c = 0; c < 8; ++c) Fde[1][c] = t1[1 ^ c];
#pragma unroll
    for (int c = 0; c < 8; ++c) t2[c] = QP2(Frt[c]);
#pragma unroll
    for (int c = 0; c < 8; ++c) Fde[2][c] = t2[2 ^ c];
#pragma unroll
    for (int c = 0; c < 8; ++c) t3[c] = QP2(t1[c]);
#pragma unroll
    for (int c = 0; c < 8; ++c) Fde[3][c] = t3[3 ^ c];
#pragma unroll
    for (int c = 0; c < 8; ++c) tt[c] = RHM(Frt[c]);
#pragma unroll
    for (int c = 0; c < 8; ++c) Fde[7][c] = tt[7 ^ c];
#pragma unroll
    for (int c = 0; c < 8; ++c) tt[c] = RHM(t1[c]);
#pragma unroll
    for (int c = 0; c < 8; ++c) Fde[6][c] = tt[6 ^ c];
#pragma unroll
    for (int c = 0; c < 8; ++c) tt[c] = RHM(t2[c]);
#pragma unroll
    for (int c = 0; c < 8; ++c) Fde[5][c] = tt[5 ^ c];
#pragma unroll
    for (int c = 0; c < 8; ++c) tt[c] = RHM(t3[c]);
#pragma unroll
    for (int c = 0; c < 8; ++c) Fde[4][c] = tt[4 ^ c];
  }

  // ---- HFd tables: HFd_i[e] = (H F)[i][r^e]  (one-time) ----
  float HFd0[8], HFd1[8];
  {
    float Hs0[8], Hs1[8];
#pragma unroll
    for (int i = 0; i < 8; ++i) { Hs0[i] = Hm[i]; Hs1[i] = Hm[8 + i]; }
    float hfc0 = 0.f, hfc1 = 0.f;   // (H F)[i][r]
#pragma unroll
    for (int jj = 0; jj < 8; ++jj) {
      const float fc = Fm[(jj << 3) | r];   // F[jj][r]
      hfc0 = fmaf(Hs0[jj], fc, hfc0);
      hfc1 = fmaf(Hs1[jj], fc, hfc1);
    }
    gather8(hfc0, HFd0);
    gather8(hfc1, HFd1);
  }

  // ---- per-group state: lane r holds m[r] and P~[d] = P[r][r^d] ----
  float m = m0[(size_t)g * 8 + r];
  float P[8];
#pragma unroll
  for (int d = 0; d < 8; ++d)
    P[d] = P0[(size_t)g * 64 + (r << 3) + (r ^ d)];

  const float* xg = x + (size_t)g * NT * 2;
  float* mo = out + (size_t)g * NT * 2;
  float* co = out + (size_t)NG * NT * 2 + (size_t)g * NT * 4;

  // ---- init measurement mean mm = H m (one-time gather) ----
  float mm0, mm1;
  {
    float MU[8];
    gather8(m, MU);
    float a = Hd0[0] * MU[0], b = Hd1[0] * MU[0];
#pragma unroll
    for (int e = 1; e < 8; ++e) {
      a = fmaf(Hd0[e], MU[e], a);
      b = fmaf(Hd1[e], MU[e], b);
    }
    mm0 = a; mm1 = b;
  }

  // ---- x double-buffer: 4-step batches ----
  float4 xa = *reinterpret_cast<const float4*>(xg);
  float4 xb = *reinterpret_cast<const float4*>(xg + 4);
  float4 na = *reinterpret_cast<const float4*>(xg + 8);
  float4 nb = *reinterpret_cast<const float4*>(xg + 12);

  // ================= full Riccati, all NT steps ==========================
#pragma unroll 1
  for (int tb = 0; tb < NT; tb += 4) {
#pragma unroll
    for (int j = 0; j < 4; ++j) {
      const int t = tb + j;
      const float x0 = (j == 0) ? xa.x : (j == 1) ? xa.z : (j == 2) ? xb.x : xb.z;
      const float x1 = (j == 0) ? xa.y : (j == 1) ? xa.w : (j == 2) ? xb.y : xb.w;

      // ---- hp_i = (H P)[i][r] via P symmetry (local) ----
      float hp0 = Hd0[0] * P[0];
      float hp1 = Hd1[0] * P[0];
#pragma unroll
      for (int c = 1; c < 8; ++c) {
        hp0 = fmaf(Hd0[c], P[c], hp0);
        hp1 = fmaf(Hd1[c], P[c], hp1);
      }

      // ---- allgather hp on LDS pipe (14 swizzle, independent) ----
      float G0[8], G1[8];
      gatherS(hp0, G0);
      gatherS(hp1, G1);

      // ---- shadow work while swizzles fly ----
      if (r == 0) *reinterpret_cast<float2*>(mo + 2 * t) = make_float2(mm0, mm1);
      const float y0 = x0 - mm0, y1 = x1 - mm1;

      // ---- S = HP H^T + R  (local redundant dots on gathered G) ----
      float sa = G0[0] * Hd0[0], sb = G0[0] * Hd1[0], sc = G1[0] * Hd1[0];
#pragma unroll
      for (int e = 1; e < 8; ++e) {
        sa = fmaf(G0[e], Hd0[e], sa);
        sb = fmaf(G0[e], Hd1[e], sb);
        sc = fmaf(G1[e], Hd1[e], sc);
      }
      const float s00 = R00 + sa, s01 = R01 + sb, s11 = R11 + sc;

      // ---- gain column r: direct 2x2 solve (exact div, absmax margin) ----
      const float det  = fmaf(s00, s11, -(s01 * s01));
      const float rdet = 1.0f / det;
      const float kt0 = fmaf(s11, hp0, -(s01 * hp1)) * rdet;
      const float kt1 = fmaf(s00, hp1, -(s01 * hp0)) * rdet;

      // ---- mu early; its gather flies under the Ct product ----
      const float mu = fmaf(kt0, y0, fmaf(kt1, y1, m));
      float MU[8];
      gatherS(mu, MU);

      if (r == 1) *reinterpret_cast<float4*>(co + 4 * t) = make_float4(s00, s01, s01, s11);

      // ---- Pu~[d] = P~[d] - kt0*G0[d] - kt1*G1[d] ----
      float Pu[8];
#pragma unroll
      for (int d = 0; d < 8; ++d)
        Pu[d] = fmaf(-kt0, G0[d], fmaf(-kt1, G1[d], P[d]));

      // ---- C = F Pu (columns, local): Ct[e] = C[r^e][r] ----
      float Ct[8];
#pragma unroll
      for (int e = 0; e < 8; ++e) {
        float acc = Fde[e][0] * Pu[0];
#pragma unroll
        for (int d = 1; d < 8; ++d) acc = fmaf(Fde[e][d], Pu[d], acc);
        Ct[e] = acc;
      }

      // ---- transpose on LDS pipe: Crow[e] = C[r][r^e] = SWZ(Ct[e], e) ----
      float Crow[8];
      Crow[0] = Ct[0];
      Crow[1] = SWZ(Ct[1], 1); Crow[2] = SWZ(Ct[2], 2);
      Crow[3] = SWZ(Ct[3], 3); Crow[4] = SWZ(Ct[4], 4);
      Crow[5] = SWZ(Ct[5], 5); Crow[6] = SWZ(Ct[6], 6);
      Crow[7] = SWZ(Ct[7], 7);

      // ---- P~[d] = Qt[d] + sum_e Fde[d][e] * Crow[e]  (in place) ----
#pragma unroll
      for (int d = 0; d < 8; ++d) {
        float acc = fmaf(Fde[d][0], Crow[0], Qt[d]);
#pragma unroll
        for (int e = 1; e < 8; ++e) acc = fmaf(Fde[d][e], Crow[e], acc);
        P[d] = acc;
      }

      // ---- mean + measurement-mean recursion (MU ready by now) ----
      float ma = Fde[0][0] * MU[0], h0 = HFd0[0] * MU[0], h1 = HFd1[0] * MU[0];
#pragma unroll
      for (int e = 1; e < 8; ++e) {
        ma = fmaf(Fde[0][e], MU[e], ma);
        h0 = fmaf(HFd0[e],  MU[e], h0);
        h1 = fmaf(HFd1[e],  MU[e], h1);
      }
      m = ma; mm0 = h0; mm1 = h1;
    }
    xa = na; xb = nb;
    int tf = tb + 8; if (tf > NT - 4) tf = NT - 4;
    na = *reinterpret_cast<const float4*>(xg + 2 * tf);
    nb = *reinterpret_cast<const float4*>(xg + 2 * tf + 4);
  }
}

extern "C" void kernel_launch(void* const* d_in, const int* in_sizes, int n_in,
                              void* d_out, int out_size, void* d_ws, size_t ws_size,
                              hipStream_t stream) {
  const float* x  = (const float*)d_in[0];
  const float* m0 = (const float*)d_in[1];
  const float* P0 = (const float*)d_in[2];
  const float* F  = (const float*)d_in[3];
  const float* Q  = (const float*)d_in[4];
  const float* H  = (const float*)d_in[5];
  const float* R  = (const float*)d_in[6];
  float* out = (float*)d_out;

  dim3 grid(NG * 8 / 256), block(256);
  hipLaunchKernelGGL(kf_kernel, grid, block, 0, stream,
                     x, m0, P0, F, Q, H, R, out);
}

// Round 18
// 161.779 us; speedup vs baseline: 1.2413x; 1.0079x over previous
//
#include <hip/hip_runtime.h>

#define NG 16384
#define NT 200

// DPP cross-lane (VALU pipe) — init only
#define DPPF(v, ctrl) __int_as_float(__builtin_amdgcn_update_dpp( \
    0, __float_as_int(v), (ctrl), 0xF, 0xF, true))
#define QP1(v) DPPF(v, 0xB1)   // src lane ^ 1
#define QP2(v) DPPF(v, 0x4E)   // src lane ^ 2
#define RHM(v) DPPF(v, 0x141)  // src lane ^ 7
// LDS-pipe xor-shuffle: lane r reads lane r^e
#define SWZ(v, e) __int_as_float(__builtin_amdgcn_ds_swizzle( \
    __float_as_int(v), ((e) << 10) | 0x1F))

// xor-allgather via DPP (7 ops) — init only
__device__ __forceinline__ void gather8(float v, float* __restrict__ o) {
  o[0] = v;
  o[1] = QP1(v);
  o[2] = QP2(v);
  o[3] = QP2(o[1]);
  o[7] = RHM(v);
  o[6] = RHM(o[1]);
  o[5] = RHM(o[2]);
  o[4] = RHM(o[3]);
}
// xor-allgather via ds_swizzle (LDS pipe, all independent)
__device__ __forceinline__ void gatherS(float v, float* __restrict__ o) {
  o[0] = v;
  o[1] = SWZ(v, 1); o[2] = SWZ(v, 2); o[3] = SWZ(v, 3); o[4] = SWZ(v, 4);
  o[5] = SWZ(v, 5); o[6] = SWZ(v, 6); o[7] = SWZ(v, 7);
}

__global__ __launch_bounds__(256, 2)
void kf_kernel(const float* __restrict__ x,
               const float* __restrict__ m0,
               const float* __restrict__ P0,
               const float* __restrict__ Fm,
               const float* __restrict__ Qm,
               const float* __restrict__ Hm,
               const float* __restrict__ Rm,
               float* __restrict__ out) {
  const int tid = threadIdx.x;
  const int r   = tid & 7;
  const int g   = blockIdx.x * 32 + (tid >> 3);

  // ---- per-lane xor-indexed parameter tables ----
  float Qt[8], Hd0[8], Hd1[8];
#pragma unroll
  for (int c = 0; c < 8; ++c) {
    Qt[c]  = Qm[(r << 3) | (r ^ c)];   // Q[r][r^c]
    Hd0[c] = Hm[r ^ c];                // H[0][r^c]
    Hd1[c] = Hm[8 + (r ^ c)];          // H[1][r^c]
  }
  const float R00 = Rm[0], R01 = Rm[1], R11 = Rm[3];

  // ---- Fde[dl][c] = F[r^dl][r^c] via DPP chains (one-time) ----
  // Fde[0][c] = F[r][r^c] also serves as the mean-recursion row.
  float Fde[8][8];
  {
    float Frt[8], t1[8], t2[8], t3[8], tt[8];
#pragma unroll
    for (int c = 0; c < 8; ++c) Frt[c] = Fm[(r << 3) | (r ^ c)];
#pragma unroll
    for (int c = 0; c < 8; ++c) Fde[0][c] = Frt[c];
#pragma unroll
    for (int c = 0; c < 8; ++c) t1[c] = QP1(Frt[c]);
#pragma unroll
    for (int c = 0; c < 8; ++c) Fde[1][c] = t1[1 ^ c];
#pragma unroll
    for (int c = 0; c < 8; ++c) t2[c] = QP2(Frt[c]);
#pragma unroll
    for (int c = 0; c < 8; ++c) Fde[2][c] = t2[2 ^ c];
#pragma unroll
    for (int c = 0; c < 8; ++c) t3[c] = QP2(t1[c]);
#pragma unroll
    for (int c = 0; c < 8; ++c) Fde[3][c] = t3[3 ^ c];
#pragma unroll
    for (int c = 0; c < 8; ++c) tt[c] = RHM(Frt[c]);
#pragma unroll
    for (int c = 0; c < 8; ++c) Fde[7][c] = tt[7 ^ c];
#pragma unroll
    for (int c = 0; c < 8; ++c) tt[c] = RHM(t1[c]);
#pragma unroll
    for (int c = 0; c < 8; ++c) Fde[6][c] = tt[6 ^ c];
#pragma unroll
    for (int c = 0; c < 8; ++c) tt[c] = RHM(t2[c]);
#pragma unroll
    for (int c = 0; c < 8; ++c) Fde[5][c] = tt[5 ^ c];
#pragma unroll
    for (int c = 0; c < 8; ++c) tt[c] = RHM(t3[c]);
#pragma unroll
    for (int c = 0; c < 8; ++c) Fde[4][c] = tt[4 ^ c];
  }

  // ---- HFd tables: HFd_i[e] = (H F)[i][r^e]  (one-time) ----
  float HFd0[8], HFd1[8];
  {
    float Hs0[8], Hs1[8];
#pragma unroll
    for (int i = 0; i < 8; ++i) { Hs0[i] = Hm[i]; Hs1[i] = Hm[8 + i]; }
    float hfc0 = 0.f, hfc1 = 0.f;   // (H F)[i][r]
#pragma unroll
    for (int jj = 0; jj < 8; ++jj) {
      const float fc = Fm[(jj << 3) | r];   // F[jj][r]
      hfc0 = fmaf(Hs0[jj], fc, hfc0);
      hfc1 = fmaf(Hs1[jj], fc, hfc1);
    }
    gather8(hfc0, HFd0);
    gather8(hfc1, HFd1);
  }

  // ---- per-group state: lane r holds m[r] and P~[d] = P[r][r^d] ----
  float m = m0[(size_t)g * 8 + r];
  float P[8];
#pragma unroll
  for (int d = 0; d < 8; ++d)
    P[d] = P0[(size_t)g * 64 + (r << 3) + (r ^ d)];

  const float* xg = x + (size_t)g * NT * 2;
  float* mo = out + (size_t)g * NT * 2;
  float* co = out + (size_t)NG * NT * 2 + (size_t)g * NT * 4;

  // ---- init measurement mean mm = H m (one-time gather) ----
  float mm0, mm1;
  {
    float MU[8];
    gather8(m, MU);
    float a = Hd0[0] * MU[0], b = Hd1[0] * MU[0];
#pragma unroll
    for (int e = 1; e < 8; ++e) {
      a = fmaf(Hd0[e], MU[e], a);
      b = fmaf(Hd1[e], MU[e], b);
    }
    mm0 = a; mm1 = b;
  }

  // ---- x double-buffer: 4-step batches ----
  float4 xa = *reinterpret_cast<const float4*>(xg);
  float4 xb = *reinterpret_cast<const float4*>(xg + 4);
  float4 na = *reinterpret_cast<const float4*>(xg + 8);
  float4 nb = *reinterpret_cast<const float4*>(xg + 12);

  // ================= full Riccati, all NT steps ==========================
#pragma unroll 1
  for (int tb = 0; tb < NT; tb += 4) {
#pragma unroll
    for (int j = 0; j < 4; ++j) {
      const int t = tb + j;
      const float x0 = (j == 0) ? xa.x : (j == 1) ? xa.z : (j == 2) ? xb.x : xb.z;
      const float x1 = (j == 0) ? xa.y : (j == 1) ? xa.w : (j == 2) ? xb.y : xb.w;

      // ---- hp_i = (H P)[i][r] via P symmetry (local) ----
      float hp0 = Hd0[0] * P[0];
      float hp1 = Hd1[0] * P[0];
#pragma unroll
      for (int c = 1; c < 8; ++c) {
        hp0 = fmaf(Hd0[c], P[c], hp0);
        hp1 = fmaf(Hd1[c], P[c], hp1);
      }

      // ---- allgather hp on LDS pipe (14 swizzle, independent) ----
      float G0[8], G1[8];
      gatherS(hp0, G0);
      gatherS(hp1, G1);

      // ---- shadow work while swizzles fly ----
      if (r == 0) *reinterpret_cast<float2*>(mo + 2 * t) = make_float2(mm0, mm1);
      const float y0 = x0 - mm0, y1 = x1 - mm1;

      // ---- S = HP H^T + R  (local redundant dots on gathered G) ----
      float sa = G0[0] * Hd0[0], sb = G0[0] * Hd1[0], sc = G1[0] * Hd1[0];
#pragma unroll
      for (int e = 1; e < 8; ++e) {
        sa = fmaf(G0[e], Hd0[e], sa);
        sb = fmaf(G0[e], Hd1[e], sb);
        sc = fmaf(G1[e], Hd1[e], sc);
      }
      const float s00 = R00 + sa, s01 = R01 + sb, s11 = R11 + sc;

      // ---- gain column r: direct 2x2 solve (exact div, absmax margin) ----
      const float det  = fmaf(s00, s11, -(s01 * s01));
      const float rdet = 1.0f / det;
      const float kt0 = fmaf(s11, hp0, -(s01 * hp1)) * rdet;
      const float kt1 = fmaf(s00, hp1, -(s01 * hp0)) * rdet;

      // ---- mu early; its gather flies under the Ct product ----
      const float mu = fmaf(kt0, y0, fmaf(kt1, y1, m));
      float MU[8];
      gatherS(mu, MU);

      if (r == 1) *reinterpret_cast<float4*>(co + 4 * t) = make_float4(s00, s01, s01, s11);

      // ---- Pu~[d] = P~[d] - kt0*G0[d] - kt1*G1[d] ----
      float Pu[8];
#pragma unroll
      for (int d = 0; d < 8; ++d)
        Pu[d] = fmaf(-kt0, G0[d], fmaf(-kt1, G1[d], P[d]));

      // ---- C = F Pu (columns, local): Ct[e] = C[r^e][r] ----
      float Ct[8];
#pragma unroll
      for (int e = 0; e < 8; ++e) {
        float acc = Fde[e][0] * Pu[0];
#pragma unroll
        for (int d = 1; d < 8; ++d) acc = fmaf(Fde[e][d], Pu[d], acc);
        Ct[e] = acc;
      }

      // ---- transpose on LDS pipe: Crow[e] = C[r][r^e] = SWZ(Ct[e], e) ----
      float Crow[8];
      Crow[0] = Ct[0];
      Crow[1] = SWZ(Ct[1], 1); Crow[2] = SWZ(Ct[2], 2);
      Crow[3] = SWZ(Ct[3], 3); Crow[4] = SWZ(Ct[4], 4);
      Crow[5] = SWZ(Ct[5], 5); Crow[6] = SWZ(Ct[6], 6);
      Crow[7] = SWZ(Ct[7], 7);

      // ---- P~[d] = Qt[d] + sum_e Fde[d][e] * Crow[e]  (in place) ----
#pragma unroll
      for (int d = 0; d < 8; ++d) {
        float acc = fmaf(Fde[d][0], Crow[0], Qt[d]);
#pragma unroll
        for (int e = 1; e < 8; ++e) acc = fmaf(Fde[d][e], Crow[e], acc);
        P[d] = acc;
      }

      // ---- mean + measurement-mean recursion (MU ready by now) ----
      float ma = Fde[0][0] * MU[0], h0 = HFd0[0] * MU[0], h1 = HFd1[0] * MU[0];
#pragma unroll
      for (int e = 1; e < 8; ++e) {
        ma = fmaf(Fde[0][e], MU[e], ma);
        h0 = fmaf(HFd0[e],  MU[e], h0);
        h1 = fmaf(HFd1[e],  MU[e], h1);
      }
      m = ma; mm0 = h0; mm1 = h1;
    }
    xa = na; xb = nb;
    int tf = tb + 8; if (tf > NT - 4) tf = NT - 4;
    na = *reinterpret_cast<const float4*>(xg + 2 * tf);
    nb = *reinterpret_cast<const float4*>(xg + 2 * tf + 4);
  }
}

extern "C" void kernel_launch(void* const* d_in, const int* in_sizes, int n_in,
                              void* d_out, int out_size, void* d_ws, size_t ws_size,
                              hipStream_t stream) {
  const float* x  = (const float*)d_in[0];
  const float* m0 = (const float*)d_in[1];
  const float* P0 = (const float*)d_in[2];
  const float* F  = (const float*)d_in[3];
  const float* Q  = (const float*)d_in[4];
  const float* H  = (const float*)d_in[5];
  const float* R  = (const float*)d_in[6];
  float* out = (float*)d_out;

  dim3 grid(NG * 8 / 256), block(256);
  hipLaunchKernelGGL(kf_kernel, grid, block, 0, stream,
                     x, m0, P0, F, Q, H, R, out);
}